// Round 1
// baseline (385.224 us; speedup 1.0000x reference)
//
#include <hip/hip_runtime.h>

#define NB 512
#define NT 512
#define NL 64

__global__ void zero_out_kernel(float* out) { *out = 0.0f; }

// One wave (64 lanes) per batch element. Lane j owns state q_j and the
// exp(trans) column E[:,j] in registers. Linear-domain forward recursion:
//   q'_j = (sum_i E_ij * q_i) * exp(em_tj),  rescale by wave-max every 4 steps.
__global__ __launch_bounds__(64) void crf_nll_kernel(
    const float* __restrict__ emission,     // B,T,L
    const int*   __restrict__ target,       // B,T
    const float* __restrict__ mask,         // B,T
    const float* __restrict__ start_trans,  // L
    const float* __restrict__ trans,        // L,L
    const float* __restrict__ end_trans,    // L
    float* __restrict__ out)
{
  const int b = blockIdx.x;
  const int j = threadIdx.x;  // 0..63

  const float* em_b = emission + (size_t)b * NT * NL;
  const float* mk_b = mask + (size_t)b * NT;
  const int*   tg_b = target + (size_t)b * NT;

  // ---------------- path score (parallel over t, then wave-reduce) ----------
  float ps = 0.0f;
  #pragma unroll
  for (int c = 0; c < NT / 64; ++c) {
    int t = c * 64 + j;
    int cur = tg_b[t];
    float m  = mk_b[t];
    float mn = (t + 1 < NT) ? mk_b[t + 1] : 0.0f;
    if (t == 0) {
      ps += start_trans[cur] + em_b[cur];              // ps0, unconditional
    } else {
      int prev = tg_b[t - 1];
      if (m > 0.5f)                                    // masked increment
        ps += trans[prev * NL + cur] + em_b[(size_t)t * NL + cur];
      if (m - mn > 0.5f)                               // end_mask = m_t & !m_{t+1}
        ps += end_trans[cur];
    }
  }
  #pragma unroll
  for (int off = 32; off; off >>= 1) ps += __shfl_down(ps, off, 64);
  // lane 0 now holds the batch path score

  // ---------------- setup: exp(trans) column in registers -------------------
  float ecol[NL];
  #pragma unroll
  for (int i = 0; i < NL; ++i) ecol[i] = __expf(trans[i * NL + j]);  // coalesced
  const float endt = __expf(end_trans[j]);

  __shared__ __align__(16) float qbuf[2][NL];

  // ---------------- forward recursion (linear domain) -----------------------
  float C = 0.0f;                               // accumulated log-scale
  float q = __expf(start_trans[j] + em_b[j]);   // t = 0 init (unmasked, per ref)
  int buf = 0;

  for (int t = 1; t < NT; ++t) {
    float m  = mk_b[t];                                 // wave-uniform
    float mn = (t + 1 < NT) ? mk_b[t + 1] : 0.0f;
    float em = em_b[(size_t)t * NL + j];                // coalesced 256B/wave
    if (m > 0.5f) {
      qbuf[buf][j] = q;
      __syncthreads();                                  // 1 wave: ~free barrier
      const float4* qv = (const float4*)qbuf[buf];      // broadcast reads
      float a0 = 0.f, a1 = 0.f, a2 = 0.f, a3 = 0.f;
      #pragma unroll
      for (int k = 0; k < 16; ++k) {
        float4 x = qv[k];
        a0 = fmaf(x.x, ecol[4 * k + 0], a0);
        a1 = fmaf(x.y, ecol[4 * k + 1], a1);
        a2 = fmaf(x.z, ecol[4 * k + 2], a2);
        a3 = fmaf(x.w, ecol[4 * k + 3], a3);
      }
      q = ((a0 + a1) + (a2 + a3)) * __expf(em);
      buf ^= 1;
    }
    if (m - mn > 0.5f) q *= endt;                       // end term (any m)
    if ((t & 3) == 3) {                                 // rescale every 4 steps
      float r = q;
      #pragma unroll
      for (int off = 32; off; off >>= 1) r = fmaxf(r, __shfl_xor(r, off, 64));
      q /= r;
      C += __logf(r);
    }
  }

  // ---------------- normalizer + output -------------------------------------
  float s = q;
  #pragma unroll
  for (int off = 32; off; off >>= 1) s += __shfl_xor(s, off, 64);
  if (j == 0) {
    float norm = __logf(s) + C;
    atomicAdd(out, (norm - ps) * (1.0f / (float)NB));
  }
}

extern "C" void kernel_launch(void* const* d_in, const int* in_sizes, int n_in,
                              void* d_out, int out_size, void* d_ws, size_t ws_size,
                              hipStream_t stream) {
  const float* emission    = (const float*)d_in[0];
  const int*   target      = (const int*)  d_in[1];
  const float* mask        = (const float*)d_in[2];
  const float* start_trans = (const float*)d_in[3];
  const float* trans       = (const float*)d_in[4];
  const float* end_trans   = (const float*)d_in[5];
  float* out = (float*)d_out;

  zero_out_kernel<<<1, 1, 0, stream>>>(out);
  crf_nll_kernel<<<NB, 64, 0, stream>>>(emission, target, mask, start_trans,
                                        trans, end_trans, out);
}

// Round 2
// 385.140 us; speedup vs baseline: 1.0002x; 1.0002x over previous
//
#include <hip/hip_runtime.h>

#define NB 512
#define NT 512
#define NL 64

__global__ void zero_out_kernel(float* out) { *out = 0.0f; }

// One wave (64 lanes) per batch element. Lane j owns state q_j and the
// exp(trans) column E[:,j] in registers. Linear-domain forward recursion:
//   q'_j = (sum_i E_ij * q_i) * exp(em_tj),  rescale by wave-max every 8 steps.
// R2: 8-deep emission prefetch FIFO, ballot-word masks, branchless step.
__global__ __launch_bounds__(64) void crf_nll_kernel(
    const float* __restrict__ emission,     // B,T,L
    const int*   __restrict__ target,       // B,T
    const float* __restrict__ mask,         // B,T
    const float* __restrict__ start_trans,  // L
    const float* __restrict__ trans,        // L,L
    const float* __restrict__ end_trans,    // L
    float* __restrict__ out)
{
  const int b = blockIdx.x;
  const int j = threadIdx.x;  // 0..63

  const float* em_b = emission + (size_t)b * NT * NL;
  const float* mk_b = mask + (size_t)b * NT;
  const int*   tg_b = target + (size_t)b * NT;

  // ---------------- path score (parallel over t, then wave-reduce) ----------
  float ps = 0.0f;
  #pragma unroll
  for (int c = 0; c < NT / 64; ++c) {
    int t = c * 64 + j;
    int cur = tg_b[t];
    float m  = mk_b[t];
    float mn = (t + 1 < NT) ? mk_b[t + 1] : 0.0f;
    if (t == 0) {
      ps += start_trans[cur] + em_b[cur];              // ps0, unconditional
    } else {
      int prev = tg_b[t - 1];
      if (m > 0.5f)                                    // masked increment
        ps += trans[prev * NL + cur] + em_b[(size_t)t * NL + cur];
      if (m - mn > 0.5f)                               // end_mask = m_t & !m_{t+1}
        ps += end_trans[cur];
    }
  }
  #pragma unroll
  for (int off = 32; off; off >>= 1) ps += __shfl_down(ps, off, 64);
  // lane 0 now holds the batch path score

  // ---------------- setup: exp(trans) column in registers -------------------
  float ecol[NL];
  #pragma unroll
  for (int i = 0; i < NL; ++i) ecol[i] = __expf(trans[i * NL + j]);  // coalesced
  const float endt = __expf(end_trans[j]);

  __shared__ __align__(16) float qbuf[NL];

  // ---------------- forward recursion (linear domain) -----------------------
  float C = 0.0f;                               // accumulated log-scale
  float q = __expf(start_trans[j] + em_b[j]);   // t = 0 init (per ref)

  // 8-deep emission prefetch FIFO: pf[t&7] holds em[t][j]
  float pf[8];
  #pragma unroll
  for (int u = 0; u < 8; ++u) pf[u] = em_b[(size_t)u * NL + j];

  for (int c = 0; c < 8; ++c) {
    const int tb = c * 64;
    // per-chunk masks as wave-uniform 64-bit words (no per-step mem traffic)
    float ml = mk_b[tb + j];
    int nidx = tb + j + 1;
    float mnext = (nidx < NT) ? mk_b[nidx] : 0.0f;
    unsigned long long mbits = __ballot(ml > 0.5f);
    unsigned long long ebits = __ballot(ml - mnext > 0.5f);
    if (c == 0) { mbits &= ~1ull; ebits &= ~1ull; }   // t=0 handled by init

    for (int i8 = 0; i8 < 64; i8 += 8) {
      #pragma unroll
      for (int u = 0; u < 8; ++u) {
        const int i = i8 + u;
        const int t = tb + i;
        float em = pf[u];
        int tp = t + 8; if (tp > NT - 1) tp = NT - 1;  // clamp: harmless re-read
        pf[u] = em_b[(size_t)tp * NL + j];             // prefetch t+8
        qbuf[j] = q;
        __syncthreads();                               // 1 wave: cheap barrier
        const float4* qv = (const float4*)qbuf;        // broadcast reads
        float a0 = 0.f, a1 = 0.f, a2 = 0.f, a3 = 0.f;
        #pragma unroll
        for (int k = 0; k < 16; ++k) {
          float4 x = qv[k];
          a0 = fmaf(x.x, ecol[4 * k + 0], a0);
          a1 = fmaf(x.y, ecol[4 * k + 1], a1);
          a2 = fmaf(x.z, ecol[4 * k + 2], a2);
          a3 = fmaf(x.w, ecol[4 * k + 3], a3);
        }
        float nxt = ((a0 + a1) + (a2 + a3)) * __expf(em);
        bool m = (mbits >> i) & 1;                     // wave-uniform scalar
        q = m ? nxt : q;
        bool e = (ebits >> i) & 1;
        q = e ? q * endt : q;
      }
      // rescale every 8 steps (growth bound e^79 < fp32 max)
      float r = q;
      #pragma unroll
      for (int off = 32; off; off >>= 1) r = fmaxf(r, __shfl_xor(r, off, 64));
      float rinv = __builtin_amdgcn_rcpf(r);
      q *= rinv;
      C += __logf(r);
    }
  }

  // ---------------- normalizer + output -------------------------------------
  float s = q;
  #pragma unroll
  for (int off = 32; off; off >>= 1) s += __shfl_xor(s, off, 64);
  if (j == 0) {
    float norm = __logf(s) + C;
    atomicAdd(out, (norm - ps) * (1.0f / (float)NB));
  }
}

extern "C" void kernel_launch(void* const* d_in, const int* in_sizes, int n_in,
                              void* d_out, int out_size, void* d_ws, size_t ws_size,
                              hipStream_t stream) {
  const float* emission    = (const float*)d_in[0];
  const int*   target      = (const int*)  d_in[1];
  const float* mask        = (const float*)d_in[2];
  const float* start_trans = (const float*)d_in[3];
  const float* trans       = (const float*)d_in[4];
  const float* end_trans   = (const float*)d_in[5];
  float* out = (float*)d_out;

  zero_out_kernel<<<1, 1, 0, stream>>>(out);
  crf_nll_kernel<<<NB, 64, 0, stream>>>(emission, target, mask, start_trans,
                                        trans, end_trans, out);
}